// Round 9
// baseline (121.665 us; speedup 1.0000x reference)
//
#include <hip/hip_runtime.h>
#include <hip/hip_bf16.h>

namespace {

constexpr int NB  = 16;
constexpr int NC  = 256;
constexpr int NHW = 16384;
constexpr int NK  = 1024;
constexpr int IGN = 255;
constexpr float SCALE = 4.5398164f;   // sqrt((1/0.07) * log2(e))
constexpr float CBIAS = 20.609929f;   // (1/0.07) * log2(e)
constexpr float LN2   = 0.69314718f;

typedef __attribute__((ext_vector_type(8))) short short8;
typedef __attribute__((ext_vector_type(4))) float f32x4;
typedef unsigned int u32;

#define ASM_VMCNT8 asm volatile("s_waitcnt vmcnt(8)" ::: "memory")
#define ASM_VMCNT0 asm volatile("s_waitcnt vmcnt(0)" ::: "memory")
#define ASM_LGKM0  asm volatile("s_waitcnt lgkmcnt(0)" ::: "memory")
#define SCHEDB     __builtin_amdgcn_sched_barrier(0)
#define MEMFENCE   asm volatile("" ::: "memory")
#define BARRIER    __builtin_amdgcn_s_barrier()
#define ACQ_AGENT  __builtin_amdgcn_fence(__ATOMIC_ACQUIRE, "agent")

__device__ __forceinline__ float fexp2(float x) { return __builtin_exp2f(x); }

__device__ __forceinline__ void gl_lds16(const void* g, void* l) {
  __builtin_amdgcn_global_load_lds((const __attribute__((address_space(1))) u32*)g,
                                   (__attribute__((address_space(3))) u32*)l, 16, 0, 0);
}

union SmemA {
  struct {                       // phase S: sampler
    int lab[NHW + (NHW >> 5)];   // padded: addr = idx + (idx>>5)
    int wtot[8];
  } s;
  struct {                       // phase G: gather
    float fbuf[64][257];
    float sqs[8][64];
    float rn[64];
  } g;
};

// ---------------------------------------------------------------- kernel 1
// Block (i, strip): redundantly sample image i (identical writes from the 16
// blocks of an image — benign), keep own strip's (lab,idx) in LDS, gather +
// normalize + pre-scale own 64 samples -> SF. Also zeroes sync counters.
__global__ __launch_bounds__(512) void pcl_prep(const int* __restrict__ labels,
                                                const float* __restrict__ feats,
                                                int* __restrict__ sel_lab,
                                                unsigned short* __restrict__ SF,
                                                int* __restrict__ fc,
                                                int* __restrict__ findone) {
  const int id = blockIdx.x;
  const int i = id & 15, strip = id >> 4;
  const int t = threadIdx.x, lane = t & 63, w = t >> 6;   // 8 waves

  __shared__ SmemA sm;
  __shared__ int slab[64], sidx[64];

  if (t == 0) { if (strip == 0) fc[i] = 0; if (id == 0) *findone = 0; }

  // ---- phase S ----
  {
    const int* lab = labels + (size_t)i * NHW;
#pragma unroll
    for (int k = 0; k < 32; ++k) {
      int idx = k * 512 + t;
      sm.s.lab[idx + (idx >> 5)] = lab[idx];
    }
    if (t < 64) slab[t] = IGN;
    __syncthreads();

    int cfg = 0, cbg = 0;
#pragma unroll
    for (int j = 0; j < 32; ++j) {
      int L = sm.s.lab[t * 33 + j];
      cfg += (L != IGN && L != 0);
      cbg += (L == 0);
    }
    int packed = cfg | (cbg << 15);
    int incl = packed;
#pragma unroll
    for (int off = 1; off < 64; off <<= 1) {
      int n = __shfl_up(incl, off);
      if (lane >= off) incl += n;
    }
    if (lane == 63) sm.s.wtot[w] = incl;
    __syncthreads();
    int wb = 0, total = 0;
#pragma unroll
    for (int ww = 0; ww < 8; ++ww) { int v = sm.s.wtot[ww]; total += v; if (ww < w) wb += v; }
    int excl = incl - packed + wb;
    int rf  = excl & 32767;
    int rbg = (excl >> 15) & 32767;
    const int nfg = total & 32767;
    const int nbg = (total >> 15) & 32767;
    const int ncap = min(NK, nfg + nbg);
    for (int k2 = ncap + t; k2 < NK; k2 += 512) sel_lab[i * NK + k2] = IGN;

    const int s0 = strip * 64;
    if (rf < NK || nfg + rbg < NK) {
      for (int j = 0; j < 32; ++j) {
        int L = sm.s.lab[t * 33 + j];
        if (L == IGN) continue;
        int slot;
        if (L != 0) { slot = rf; ++rf; }
        else        { slot = nfg + rbg; ++rbg; }
        if (slot < NK) {
          sel_lab[i * NK + slot] = L;
          int d = slot - s0;
          if ((unsigned)d < 64u) { slab[d] = L; sidx[d] = t * 32 + j; }
        }
      }
    }
    __syncthreads();
  }

  // ---- phase G ----
  {
    const int ss = t & 63, w8 = t >> 6;
    const int lb = slab[ss];
    const int p = (lb != IGN) ? sidx[ss] : -1;
    const float* fb = feats + (size_t)i * NC * NHW;
    float sq = 0.f;
#pragma unroll
    for (int cc = 0; cc < 32; ++cc) {
      int c = w8 * 32 + cc;
      float v = (p >= 0) ? fb[(size_t)c * NHW + p] : 0.f;
      sm.g.fbuf[ss][c] = v;
      sq += v * v;
    }
    sm.g.sqs[w8][ss] = sq;
    __syncthreads();
    if (t < 64) {
      float tot = 0.f;
#pragma unroll
      for (int k2 = 0; k2 < 8; ++k2) tot += sm.g.sqs[k2][t];
      sm.g.rn[t] = SCALE / fmaxf(sqrtf(tot), 1e-12f);
    }
    __syncthreads();
    unsigned short* SFo = SF + ((size_t)(i * NK + strip * 64)) * NC;
#pragma unroll
    for (int it2 = 0; it2 < 4; ++it2) {
      int n = it2 * 512 + t;
      int row = n >> 5, ch16 = n & 31;
      float r = sm.g.rn[row];
      short8 v8;
#pragma unroll
      for (int e = 0; e < 8; ++e) {
        float x = sm.g.fbuf[row][ch16 * 8 + e] * r;
        __hip_bfloat16 h = __float2bfloat16(x);
        unsigned short u; __builtin_memcpy(&u, &h, 2);
        v8[e] = (short)u;
      }
      *(short8*)(SFo + (size_t)row * NC + ch16 * 8) = v8;
    }
  }
}

// ---------------------------------------------------------------- kernel 2
// Block (i, strip): 64 rows of image i vs 2048 cols (self 1024 + next 1024).
// 8 waves = (rw 0..1: 32-row half) x (ch4 0..3: 32-col quarter). 16x16x32
// MFMA. SINGLE barrier per round (T3 cadence): BARRIER -> stage(r+1) ->
// vmcnt(8) -> compute(r). Cross col sums written as per-rw-half partials
// (Cp2) so no in-round LDS exchange. End: counter dance -> pair fold -> loss.
__global__ __launch_bounds__(512) void pcl_tiles(
    const unsigned short* __restrict__ SF, const int* __restrict__ sel_lab,
    float2* __restrict__ SNd, float4* __restrict__ Rii, float4* __restrict__ Cp2,
    float2* __restrict__ A1arr, float2* __restrict__ Aimg,
    int* __restrict__ fc, int* __restrict__ findone, float* __restrict__ out) {
  const int id = blockIdx.x;
  const int i = id & 15, strip = id >> 4;
  const int inxt = (i + 1) & 15, iprev = (i + 15) & 15;
  const int t = threadIdx.x, lane = t & 63, w = t >> 6;
  const int rw = w & 1, ch4 = w >> 1;
  const int lg = lane >> 4, lr = lane & 15;
  const float SFAC = __builtin_exp2f(-CBIAS);

  __shared__ short buf[2][128 * 256];          // 128 KB
  __shared__ float4 rredS[4][64];              // 4 KB
  __shared__ float4 rredX[4][64];              // 4 KB
  __shared__ float2 fold2[8];
  __shared__ int fA, fB;

  const unsigned short* SFrow = SF + (size_t)i * (NK * NC) + strip * 64 * NC;

  auto stage_round = [&](int rr) {
    const unsigned short* base =
        SF + (size_t)((rr < 8) ? i : inxt) * (NK * NC) + ((rr & 7) * 128) * NC;
    short* dst = buf[rr & 1];
#pragma unroll
    for (int it = 0; it < 8; ++it) {
      int n = it * 512 + t, row = n >> 5, ch = n & 31;
      gl_lds16(base + row * NC + ((ch ^ (row & 15)) << 3), dst + (size_t)n * 8);
    }
  };

  // ---- prologue: rows -> buf0, afrag, then stage round 0 only (depth-1) ----
#pragma unroll
  for (int it = 0; it < 4; ++it) {
    int n = it * 512 + t, row = n >> 5, ch = n & 31;
    gl_lds16(SFrow + row * NC + ((ch ^ (row & 15)) << 3), buf[0] + (size_t)n * 8);
  }
  ASM_VMCNT0; MEMFENCE; BARRIER; MEMFENCE;

  short8 afrag[2][8];
#pragma unroll
  for (int rt = 0; rt < 2; ++rt) {
    const int arow = rw * 32 + rt * 16 + lr;
#pragma unroll
    for (int ks = 0; ks < 8; ++ks) {
      int ch = ks * 4 + lg;
      afrag[rt][ks] = *(const short8*)(buf[0] + arow * 256 + ((ch ^ (arow & 15)) << 3));
    }
  }
  ASM_LGKM0; SCHEDB; MEMFENCE; BARRIER; MEMFENCE;   // buf0 free

  stage_round(0);

  int rlab[2][4];
#pragma unroll
  for (int rt = 0; rt < 2; ++rt)
#pragma unroll
    for (int jj = 0; jj < 4; ++jj) {
      int L = sel_lab[i * NK + strip * 64 + rw * 32 + rt * 16 + 4 * lg + jj];
      rlab[rt][jj] = (L == IGN) ? -1 : L;
    }

  float SA[2][4], NPr[2][4], PEr[2][4], ETr[2][4];
#pragma unroll
  for (int rt = 0; rt < 2; ++rt)
#pragma unroll
    for (int jj = 0; jj < 4; ++jj) { SA[rt][jj] = 0.f; NPr[rt][jj] = 0.f; PEr[rt][jj] = 0.f; ETr[rt][jj] = 0.f; }

  float SX[2][4], NX[2][4], PX[2][4];
#pragma unroll
  for (int rt = 0; rt < 2; ++rt)
#pragma unroll
    for (int jj = 0; jj < 4; ++jj) { SX[rt][jj] = 0.f; NX[rt][jj] = 0.f; PX[rt][jj] = 0.f; }

  const int rs = strip >> 1;                    // diag round
  const bool dwave = ((ch4 >> 1) == (strip & 1));

  // ================= 16 rounds (0..7 self, 8..15 cross) =================
  for (int r = 0; r < 16; ++r) {
    MEMFENCE; BARRIER; MEMFENCE;               // all waves done with buf[(r+1)&1]
    if (r < 15) { stage_round(r + 1); ASM_VMCNT8; }
    else        { ASM_VMCNT0; }
    MEMFENCE;

    const int jimg = (r < 8) ? i : inxt;
    int cl[2]; float cvf[2];
#pragma unroll
    for (int c2 = 0; c2 < 2; ++c2) {
      int L = sel_lab[jimg * NK + (r & 7) * 128 + ch4 * 32 + c2 * 16 + lr];
      cl[c2] = (L == IGN) ? -2 : L;
      cvf[c2] = (L == IGN) ? 0.f : 1.f;
    }

    const short* bb = buf[r & 1];
    f32x4 acc[2][2];
#pragma unroll
    for (int rt = 0; rt < 2; ++rt)
#pragma unroll
      for (int c2 = 0; c2 < 2; ++c2) acc[rt][c2] = f32x4{0.f, 0.f, 0.f, 0.f};
#pragma unroll
    for (int ks = 0; ks < 8; ++ks) {
      int ch = ks * 4 + lg;
      short8 b0, b1;
      {
        int br0 = ch4 * 32 + lr, br1 = ch4 * 32 + 16 + lr;
        b0 = *(const short8*)(bb + br0 * 256 + ((ch ^ (br0 & 15)) << 3));
        b1 = *(const short8*)(bb + br1 * 256 + ((ch ^ (br1 & 15)) << 3));
      }
      acc[0][0] = __builtin_amdgcn_mfma_f32_16x16x32_bf16(afrag[0][ks], b0, acc[0][0], 0, 0, 0);
      acc[0][1] = __builtin_amdgcn_mfma_f32_16x16x32_bf16(afrag[0][ks], b1, acc[0][1], 0, 0, 0);
      acc[1][0] = __builtin_amdgcn_mfma_f32_16x16x32_bf16(afrag[1][ks], b0, acc[1][0], 0, 0, 0);
      acc[1][1] = __builtin_amdgcn_mfma_f32_16x16x32_bf16(afrag[1][ks], b1, acc[1][1], 0, 0, 0);
    }

    if (r < 8) {
      const bool isdiag = (r == rs) && dwave;
#pragma unroll
      for (int rt = 0; rt < 2; ++rt)
#pragma unroll
        for (int c2 = 0; c2 < 2; ++c2) {
          const int clc = cl[c2]; const float cvc = cvf[c2];
          const int gc = r * 128 + ch4 * 32 + c2 * 16 + lr;
          const int grb = strip * 64 + rw * 32 + rt * 16 + 4 * lg;
#pragma unroll
          for (int jj = 0; jj < 4; ++jj) {
            float a = acc[rt][c2][jj];
            float E = fexp2(a);
            float Ev = cvc * E;
            float pm = (rlab[rt][jj] == clc) ? 1.f : 0.f;
            if (isdiag) {
              bool ok = (grb + jj) != gc;
              pm = ok ? pm : 0.f;
              Ev = ok ? Ev : 0.f;
            }
            SA[rt][jj] += pm * a; NPr[rt][jj] += pm;
            PEr[rt][jj] += pm * Ev; ETr[rt][jj] += Ev;
          }
        }
    } else {
      float cS[2], cN[2], cE[2];
#pragma unroll
      for (int c2 = 0; c2 < 2; ++c2) { cS[c2] = 0.f; cN[c2] = 0.f; cE[c2] = 0.f; }
#pragma unroll
      for (int rt = 0; rt < 2; ++rt)
#pragma unroll
        for (int c2 = 0; c2 < 2; ++c2) {
          const int clc = cl[c2];
#pragma unroll
          for (int jj = 0; jj < 4; ++jj) {
            float a = acc[rt][c2][jj];
            float E = fexp2(a);
            float pm = (rlab[rt][jj] == clc) ? 1.f : 0.f;
            float pa = pm * a, pe = pm * E;
            SX[rt][jj] += pa; NX[rt][jj] += pm; PX[rt][jj] += pe;
            cS[c2] += pa; cN[c2] += pm; cE[c2] += pe;
          }
        }
#pragma unroll
      for (int c2 = 0; c2 < 2; ++c2) {
        cS[c2] += __shfl_xor(cS[c2], 16); cS[c2] += __shfl_xor(cS[c2], 32);
        cN[c2] += __shfl_xor(cN[c2], 16); cN[c2] += __shfl_xor(cN[c2], 32);
        cE[c2] += __shfl_xor(cE[c2], 16); cE[c2] += __shfl_xor(cE[c2], 32);
        if (lg == 0) {
          Cp2[((size_t)(i * 16 + strip) * 2 + rw) * NK + (r & 7) * 128 + ch4 * 32 + c2 * 16 + lr] =
              make_float4(cS[c2], cN[c2], cE[c2] * SFAC, 0.f);
        }
      }
    }
  }

  // ---- fold self stats -> rredS, cross -> rredX ----
#pragma unroll
  for (int rt = 0; rt < 2; ++rt)
#pragma unroll
    for (int jj = 0; jj < 4; ++jj) {
      float a = SA[rt][jj], b4 = NPr[rt][jj], c4 = PEr[rt][jj], d4 = ETr[rt][jj];
      float x = SX[rt][jj], y4 = NX[rt][jj], z4 = PX[rt][jj];
#pragma unroll
      for (int m = 1; m <= 8; m <<= 1) {
        a += __shfl_xor(a, m); b4 += __shfl_xor(b4, m);
        c4 += __shfl_xor(c4, m); d4 += __shfl_xor(d4, m);
        x += __shfl_xor(x, m); y4 += __shfl_xor(y4, m); z4 += __shfl_xor(z4, m);
      }
      if (lr == 0) {
        rredS[ch4][rw * 32 + rt * 16 + 4 * lg + jj] = make_float4(a, b4, c4, d4);
        rredX[ch4][rw * 32 + rt * 16 + 4 * lg + jj] = make_float4(x, y4, z4, 0.f);
      }
    }
  __syncthreads();

  // ---- per-row pass: SNd/Rii writes + local a1 ----
  if (t < 64) {
    float4 sS = rredS[0][t], sX = rredX[0][t];
#pragma unroll
    for (int c4 = 1; c4 < 4; ++c4) {
      float4 u = rredS[c4][t], v = rredX[c4][t];
      sS.x += u.x; sS.y += u.y; sS.z += u.z; sS.w += u.w;
      sX.x += v.x; sX.y += v.y; sX.z += v.z;
    }
    float SNL = sS.w - sS.z;
    float SN = SNL * SFAC + 1e-8f;
    float LSN = __logf(SN), rSN = 1.f / SN;
    int g = i * NK + strip * 64 + t;
    SNd[g] = make_float2(LSN, rSN);
    Rii[g] = make_float4(sS.x, sS.y, sS.z * SFAC, 0.f);
    float pps = LN2 * (sS.x - CBIAS * sS.y) - sS.y * LSN - rSN * (sS.z * SFAC);
    float ppx = LN2 * (sX.x - CBIAS * sX.y) - sX.y * LSN - rSN * (sX.z * SFAC);
    float np1 = sS.y + sX.y;
    float an = 0.f, ac = 0.f;
    if (np1 > 0.f) { an = -(pps + ppx) / np1; ac = 1.f; }
#pragma unroll
    for (int m = 1; m <= 32; m <<= 1) { an += __shfl_xor(an, m); ac += __shfl_xor(ac, m); }
    if (t == 0) A1arr[i * 16 + strip] = make_float2(an, ac);
  }
  __syncthreads();

  // ---- counter dance ----
  if (t == 0) {
    __threadfence();
    int o1 = atomicAdd(&fc[i], 1);
    int o2 = atomicAdd(&fc[iprev], 1);
    fA = (o1 == 31); fB = (o2 == 31);
  }
  __syncthreads();

  auto pair_fold = [&](int p) {
    const int q = (p + 1) & 15;
    ACQ_AGENT;
    float an = 0.f, ac = 0.f;
    for (int r2 = t; r2 < NK; r2 += 512) {
      float4 rii = Rii[q * NK + r2];
      float2 sn = SNd[q * NK + r2];
      float cs = 0.f, cn = 0.f, ce = 0.f;
#pragma unroll
      for (int s2 = 0; s2 < 16; ++s2) {
#pragma unroll
        for (int h = 0; h < 2; ++h) {
          float4 c = Cp2[((size_t)(p * 16 + s2) * 2 + h) * NK + r2];
          cs += c.x; cn += c.y; ce += c.z;
        }
      }
      float ppc = LN2 * (cs - CBIAS * cn) - cn * sn.x - sn.y * ce;
      float ppi = LN2 * (rii.x - CBIAS * rii.y) - rii.y * sn.x - sn.y * rii.z;
      float np2 = rii.y + cn;
      if (np2 > 0.f) { an -= (ppi + ppc) / np2; ac += 1.f; }
    }
#pragma unroll
    for (int m = 1; m <= 32; m <<= 1) { an += __shfl_xor(an, m); ac += __shfl_xor(ac, m); }
    if (lane == 0) fold2[w] = make_float2(an, ac);
    __syncthreads();
    if (t == 0) {
      float a2n = 0.f, a2c = 0.f;
#pragma unroll
      for (int k2 = 0; k2 < 8; ++k2) { a2n += fold2[k2].x; a2c += fold2[k2].y; }
      float a1n = 0.f, a1c = 0.f;
#pragma unroll
      for (int s2 = 0; s2 < 16; ++s2) {
        float2 a = A1arr[q * 16 + s2];
        a1n += a.x; a1c += a.y;
      }
      Aimg[q] = make_float2(a1n + a2n, a1c + a2c);
      __threadfence();
      int f = atomicAdd(findone, 1);
      if (f == NB - 1) {
        ACQ_AGENT;
        float v = 0.f;
#pragma unroll
        for (int im = 0; im < NB; ++im) {
          float2 gg = Aimg[im];
          v += gg.x / fmaxf(gg.y, 1.f);
        }
        out[0] = v / (float)NB;
      }
    }
    __syncthreads();
  };

  if (fA) pair_fold(i);
  if (fB) pair_fold(iprev);
}

}  // namespace

extern "C" void kernel_launch(void* const* d_in, const int* in_sizes, int n_in,
                              void* d_out, int out_size, void* d_ws, size_t ws_size,
                              hipStream_t stream) {
  (void)in_sizes; (void)n_in; (void)out_size; (void)ws_size;
  const float* feats  = (const float*)d_in[0];
  const int*   labels = (const int*)d_in[1];
  float* out = (float*)d_out;
  char* ws = (char*)d_ws;

  int* sel_lab = (int*)ws;                                       // 64 KB
  unsigned short* SF = (unsigned short*)(ws + (64 << 10));       // 8 MB
  size_t off = (64 << 10) + (size_t)NB * NK * NC * 2;
  float2* SNd = (float2*)(ws + off);  off += (size_t)NB * NK * 8;           // 128 KB
  float4* Rii = (float4*)(ws + off);  off += (size_t)NB * NK * 16;          // 256 KB
  float4* Cp2 = (float4*)(ws + off);  off += (size_t)NB * 16 * 2 * NK * 16; // 8 MB
  float2* A1arr = (float2*)(ws + off); off += (size_t)NB * 16 * 8;
  float2* Aimg = (float2*)(ws + off);  off += NB * 8;
  int* fc = (int*)(ws + off);          off += 16 * 4;
  int* findone = (int*)(ws + off);

  pcl_prep<<<256, 512, 0, stream>>>(labels, feats, sel_lab, SF, fc, findone);
  pcl_tiles<<<256, 512, 0, stream>>>(SF, sel_lab, SNd, Rii, Cp2,
                                     A1arr, Aimg, fc, findone, out);
}

// Round 10
// 91.351 us; speedup vs baseline: 1.3318x; 1.3318x over previous
//
#include <hip/hip_runtime.h>
#include <hip/hip_bf16.h>

namespace {

constexpr int NB  = 16;
constexpr int NC  = 256;
constexpr int NHW = 16384;
constexpr int NK  = 1024;
constexpr int IGN = 255;
constexpr float SCALE = 4.5398164f;   // sqrt((1/0.07) * log2(e))
constexpr float CBIAS = 20.609929f;   // (1/0.07) * log2(e)
constexpr float LN2   = 0.69314718f;

typedef __attribute__((ext_vector_type(8))) short short8;
typedef __attribute__((ext_vector_type(4))) float f32x4;
typedef unsigned int u32;

#define ASM_VMCNT8 asm volatile("s_waitcnt vmcnt(8)" ::: "memory")
#define ASM_VMCNT0 asm volatile("s_waitcnt vmcnt(0)" ::: "memory")
#define ASM_LGKM0  asm volatile("s_waitcnt lgkmcnt(0)" ::: "memory")
#define SCHEDB     __builtin_amdgcn_sched_barrier(0)
#define MEMFENCE   asm volatile("" ::: "memory")
#define BARRIER    __builtin_amdgcn_s_barrier()
#define ACQ_AGENT  __builtin_amdgcn_fence(__ATOMIC_ACQUIRE, "agent")

__device__ __forceinline__ float fexp2(float x) { return __builtin_exp2f(x); }

__device__ __forceinline__ void gl_lds16(const void* g, void* l) {
  __builtin_amdgcn_global_load_lds((const __attribute__((address_space(1))) u32*)g,
                                   (__attribute__((address_space(3))) u32*)l, 16, 0, 0);
}

union SmemA {
  struct {                       // phase S: sampler
    int lab[NHW + (NHW >> 5)];   // padded: addr = idx + (idx>>5)
    int wtot[8];
  } s;
  struct {                       // phase G: gather
    float fbuf[64][257];
    float sqs[8][64];
    float rn[64];
  } g;
};

// ---------------------------------------------------------------- kernel 1
// Block (i, strip): sample image i locally (prefix scan only — no global
// dependency), keep own strip's (lab,idx) in LDS; ONLY the strip-0 block of
// each image writes sel_lab (single writer -> no cross-XCD store contention).
// Then gather + normalize + pre-scale own 64 samples -> SF.
__global__ __launch_bounds__(512) void pcl_prep(const int* __restrict__ labels,
                                                const float* __restrict__ feats,
                                                int* __restrict__ sel_lab,
                                                unsigned short* __restrict__ SF,
                                                int* __restrict__ cnt,
                                                int* __restrict__ findone) {
  const int id = blockIdx.x;
  const int i = id & 15, strip = id >> 4;
  const bool wr = (strip == 0);
  const int t = threadIdx.x, lane = t & 63, w = t >> 6;   // 8 waves

  __shared__ SmemA sm;
  __shared__ int slab[64], sidx[64];

  if (t == 0) { if (wr) cnt[i] = 0; if (id == 0) *findone = 0; }

  // ---- phase S ----
  {
    const int* lab = labels + (size_t)i * NHW;
#pragma unroll
    for (int k = 0; k < 32; ++k) {
      int idx = k * 512 + t;
      sm.s.lab[idx + (idx >> 5)] = lab[idx];
    }
    if (t < 64) slab[t] = IGN;
    __syncthreads();

    int cfg = 0, cbg = 0;
#pragma unroll
    for (int j = 0; j < 32; ++j) {
      int L = sm.s.lab[t * 33 + j];
      cfg += (L != IGN && L != 0);
      cbg += (L == 0);
    }
    int packed = cfg | (cbg << 15);
    int incl = packed;
#pragma unroll
    for (int off = 1; off < 64; off <<= 1) {
      int n = __shfl_up(incl, off);
      if (lane >= off) incl += n;
    }
    if (lane == 63) sm.s.wtot[w] = incl;
    __syncthreads();
    int wb = 0, total = 0;
#pragma unroll
    for (int ww = 0; ww < 8; ++ww) { int v = sm.s.wtot[ww]; total += v; if (ww < w) wb += v; }
    int excl = incl - packed + wb;
    int rf  = excl & 32767;
    int rbg = (excl >> 15) & 32767;
    const int nfg = total & 32767;
    const int nbg = (total >> 15) & 32767;
    const int ncap = min(NK, nfg + nbg);
    if (wr) {
      for (int k2 = ncap + t; k2 < NK; k2 += 512) sel_lab[i * NK + k2] = IGN;
    }

    const int s0 = strip * 64;
    if (rf < NK || nfg + rbg < NK) {
      for (int j = 0; j < 32; ++j) {
        int L = sm.s.lab[t * 33 + j];
        if (L == IGN) continue;
        int slot;
        if (L != 0) { slot = rf; ++rf; }
        else        { slot = nfg + rbg; ++rbg; }
        if (slot < NK) {
          if (wr) sel_lab[i * NK + slot] = L;
          int d = slot - s0;
          if ((unsigned)d < 64u) { slab[d] = L; sidx[d] = t * 32 + j; }
        }
      }
    }
    __syncthreads();
  }

  // ---- phase G ----
  {
    const int ss = t & 63, w8 = t >> 6;
    const int lb = slab[ss];
    const int p = (lb != IGN) ? sidx[ss] : -1;
    const float* fb = feats + (size_t)i * NC * NHW;
    float sq = 0.f;
#pragma unroll
    for (int cc = 0; cc < 32; ++cc) {
      int c = w8 * 32 + cc;
      float v = (p >= 0) ? fb[(size_t)c * NHW + p] : 0.f;
      sm.g.fbuf[ss][c] = v;
      sq += v * v;
    }
    sm.g.sqs[w8][ss] = sq;
    __syncthreads();
    if (t < 64) {
      float tot = 0.f;
#pragma unroll
      for (int k2 = 0; k2 < 8; ++k2) tot += sm.g.sqs[k2][t];
      sm.g.rn[t] = SCALE / fmaxf(sqrtf(tot), 1e-12f);
    }
    __syncthreads();
    unsigned short* SFo = SF + ((size_t)(i * NK + strip * 64)) * NC;
#pragma unroll
    for (int it2 = 0; it2 < 4; ++it2) {
      int n = it2 * 512 + t;
      int row = n >> 5, ch16 = n & 31;
      float r = sm.g.rn[row];
      short8 v8;
#pragma unroll
      for (int e = 0; e < 8; ++e) {
        float x = sm.g.fbuf[row][ch16 * 8 + e] * r;
        __hip_bfloat16 h = __float2bfloat16(x);
        unsigned short u; __builtin_memcpy(&u, &h, 2);
        v8[e] = (short)u;
      }
      *(short8*)(SFo + (size_t)row * NC + ch16 * 8) = v8;
    }
  }
}

// ---------------------------------------------------------------- kernel 2
// R6-proven tiles kernel, byte-identical. Block (i, strip): 64 rows of image
// i vs 2048 cols (self 1024 + next 1024). 8 waves = (rw 0..1) x (ch4 0..3).
// 16x16x32 MFMA, 2-barrier cadence, depth-2 prefetch, counted vmcnt.
__global__ __launch_bounds__(512) void pcl_tiles(
    const unsigned short* __restrict__ SF, const int* __restrict__ sel_lab,
    float2* __restrict__ SNd, float4* __restrict__ Rii, float4* __restrict__ Cp,
    float2* __restrict__ A1arr, float2* __restrict__ Aimg,
    int* __restrict__ cnt, int* __restrict__ findone, float* __restrict__ out) {
  const int id = blockIdx.x;
  const int i = id & 15, strip = id >> 4;
  const int inxt = (i + 1) & 15, iprev = (i + 15) & 15;
  const int t = threadIdx.x, lane = t & 63, w = t >> 6;
  const int rw = w & 1, ch4 = w >> 1;
  const int lg = lane >> 4, lr = lane & 15;
  const float SFAC = __builtin_exp2f(-CBIAS);

  __shared__ short buf[2][128 * 256];          // 128 KB
  __shared__ float4 colAcc[2][128];            // 4 KB
  __shared__ float4 rredS[4][64];              // 4 KB
  __shared__ float4 rredX[4][64];              // 4 KB
  __shared__ float2 fold2[8];
  __shared__ int fA, fB;

  const unsigned short* SFrow = SF + (size_t)i * (NK * NC) + strip * 64 * NC;

  auto stage_round = [&](int rr) {
    const unsigned short* base =
        SF + (size_t)((rr < 8) ? i : inxt) * (NK * NC) + ((rr & 7) * 128) * NC;
    short* dst = buf[rr & 1];
#pragma unroll
    for (int it = 0; it < 8; ++it) {
      int n = it * 512 + t, row = n >> 5, ch = n & 31;
      gl_lds16(base + row * NC + ((ch ^ (row & 15)) << 3), dst + (size_t)n * 8);
    }
  };

  // ---- prologue ----
#pragma unroll
  for (int it = 0; it < 4; ++it) {
    int n = it * 512 + t, row = n >> 5, ch = n & 31;
    gl_lds16(SFrow + row * NC + ((ch ^ (row & 15)) << 3), buf[0] + (size_t)n * 8);
  }
  ASM_VMCNT0; MEMFENCE; BARRIER; MEMFENCE;

  short8 afrag[2][8];
#pragma unroll
  for (int rt = 0; rt < 2; ++rt) {
    const int arow = rw * 32 + rt * 16 + lr;
#pragma unroll
    for (int ks = 0; ks < 8; ++ks) {
      int ch = ks * 4 + lg;
      afrag[rt][ks] = *(const short8*)(buf[0] + arow * 256 + ((ch ^ (arow & 15)) << 3));
    }
  }
  ASM_LGKM0; SCHEDB; MEMFENCE; BARRIER; MEMFENCE;   // buf0 free

  stage_round(0);
  stage_round(1);

  int rlab[2][4];
#pragma unroll
  for (int rt = 0; rt < 2; ++rt)
#pragma unroll
    for (int jj = 0; jj < 4; ++jj) {
      int L = sel_lab[i * NK + strip * 64 + rw * 32 + rt * 16 + 4 * lg + jj];
      rlab[rt][jj] = (L == IGN) ? -1 : L;
    }

  ASM_VMCNT8; MEMFENCE; BARRIER; MEMFENCE;     // round 0 ready

  float SA[2][4], NPr[2][4], PEr[2][4], ETr[2][4];
#pragma unroll
  for (int rt = 0; rt < 2; ++rt)
#pragma unroll
    for (int jj = 0; jj < 4; ++jj) { SA[rt][jj] = 0.f; NPr[rt][jj] = 0.f; PEr[rt][jj] = 0.f; ETr[rt][jj] = 0.f; }

  const int rs = strip >> 1;                    // diag round
  const bool dwave = ((ch4 >> 1) == (strip & 1));

  // ================= SELF rounds 0..7 =================
  for (int r = 0; r < 8; ++r) {
    int cl[2]; float cvf[2];
#pragma unroll
    for (int c2 = 0; c2 < 2; ++c2) {
      int L = sel_lab[i * NK + r * 128 + ch4 * 32 + c2 * 16 + lr];
      cl[c2] = (L == IGN) ? -2 : L;
      cvf[c2] = (L == IGN) ? 0.f : 1.f;
    }

    const short* bb = buf[r & 1];
    f32x4 acc[2][2];
#pragma unroll
    for (int rt = 0; rt < 2; ++rt)
#pragma unroll
      for (int c2 = 0; c2 < 2; ++c2) acc[rt][c2] = f32x4{0.f, 0.f, 0.f, 0.f};
#pragma unroll
    for (int ks = 0; ks < 8; ++ks) {
      int ch = ks * 4 + lg;
      short8 b0, b1;
      {
        int br0 = ch4 * 32 + lr, br1 = ch4 * 32 + 16 + lr;
        b0 = *(const short8*)(bb + br0 * 256 + ((ch ^ (br0 & 15)) << 3));
        b1 = *(const short8*)(bb + br1 * 256 + ((ch ^ (br1 & 15)) << 3));
      }
      acc[0][0] = __builtin_amdgcn_mfma_f32_16x16x32_bf16(afrag[0][ks], b0, acc[0][0], 0, 0, 0);
      acc[0][1] = __builtin_amdgcn_mfma_f32_16x16x32_bf16(afrag[0][ks], b1, acc[0][1], 0, 0, 0);
      acc[1][0] = __builtin_amdgcn_mfma_f32_16x16x32_bf16(afrag[1][ks], b0, acc[1][0], 0, 0, 0);
      acc[1][1] = __builtin_amdgcn_mfma_f32_16x16x32_bf16(afrag[1][ks], b1, acc[1][1], 0, 0, 0);
    }

    const bool isdiag = (r == rs) && dwave;
#pragma unroll
    for (int rt = 0; rt < 2; ++rt)
#pragma unroll
      for (int c2 = 0; c2 < 2; ++c2) {
        const int clc = cl[c2]; const float cvc = cvf[c2];
        const int gc = r * 128 + ch4 * 32 + c2 * 16 + lr;
        const int grb = strip * 64 + rw * 32 + rt * 16 + 4 * lg;
#pragma unroll
        for (int jj = 0; jj < 4; ++jj) {
          float a = acc[rt][c2][jj];
          float E = fexp2(a);
          float Ev = cvc * E;
          float pm = (rlab[rt][jj] == clc) ? 1.f : 0.f;
          if (isdiag) {
            bool ok = (grb + jj) != gc;
            pm = ok ? pm : 0.f;
            Ev = ok ? Ev : 0.f;
          }
          SA[rt][jj] += pm * a; NPr[rt][jj] += pm;
          PEr[rt][jj] += pm * Ev; ETr[rt][jj] += Ev;
        }
      }

    MEMFENCE; BARRIER; MEMFENCE;
    stage_round(r + 2);
    ASM_VMCNT8;
    MEMFENCE; BARRIER; MEMFENCE;
  }

  // ---- self fold -> rredS ----
#pragma unroll
  for (int rt = 0; rt < 2; ++rt)
#pragma unroll
    for (int jj = 0; jj < 4; ++jj) {
      float a = SA[rt][jj], b4 = NPr[rt][jj], c4 = PEr[rt][jj], d4 = ETr[rt][jj];
#pragma unroll
      for (int m = 1; m <= 8; m <<= 1) {
        a += __shfl_xor(a, m); b4 += __shfl_xor(b4, m);
        c4 += __shfl_xor(c4, m); d4 += __shfl_xor(d4, m);
      }
      if (lr == 0) rredS[ch4][rw * 32 + rt * 16 + 4 * lg + jj] = make_float4(a, b4, c4, d4);
    }

  float SX[2][4], NX[2][4], PX[2][4];
#pragma unroll
  for (int rt = 0; rt < 2; ++rt)
#pragma unroll
    for (int jj = 0; jj < 4; ++jj) { SX[rt][jj] = 0.f; NX[rt][jj] = 0.f; PX[rt][jj] = 0.f; }

  // ================= CROSS rounds 8..15 =================
  for (int r = 8; r < 16; ++r) {
    int cl[2];
#pragma unroll
    for (int c2 = 0; c2 < 2; ++c2) {
      int L = sel_lab[inxt * NK + (r & 7) * 128 + ch4 * 32 + c2 * 16 + lr];
      cl[c2] = (L == IGN) ? -2 : L;
    }

    const short* bb = buf[r & 1];
    f32x4 acc[2][2];
#pragma unroll
    for (int rt = 0; rt < 2; ++rt)
#pragma unroll
      for (int c2 = 0; c2 < 2; ++c2) acc[rt][c2] = f32x4{0.f, 0.f, 0.f, 0.f};
#pragma unroll
    for (int ks = 0; ks < 8; ++ks) {
      int ch = ks * 4 + lg;
      short8 b0, b1;
      {
        int br0 = ch4 * 32 + lr, br1 = ch4 * 32 + 16 + lr;
        b0 = *(const short8*)(bb + br0 * 256 + ((ch ^ (br0 & 15)) << 3));
        b1 = *(const short8*)(bb + br1 * 256 + ((ch ^ (br1 & 15)) << 3));
      }
      acc[0][0] = __builtin_amdgcn_mfma_f32_16x16x32_bf16(afrag[0][ks], b0, acc[0][0], 0, 0, 0);
      acc[0][1] = __builtin_amdgcn_mfma_f32_16x16x32_bf16(afrag[0][ks], b1, acc[0][1], 0, 0, 0);
      acc[1][0] = __builtin_amdgcn_mfma_f32_16x16x32_bf16(afrag[1][ks], b0, acc[1][0], 0, 0, 0);
      acc[1][1] = __builtin_amdgcn_mfma_f32_16x16x32_bf16(afrag[1][ks], b1, acc[1][1], 0, 0, 0);
    }

    float cS[2], cN[2], cE[2];
#pragma unroll
    for (int c2 = 0; c2 < 2; ++c2) { cS[c2] = 0.f; cN[c2] = 0.f; cE[c2] = 0.f; }
#pragma unroll
    for (int rt = 0; rt < 2; ++rt)
#pragma unroll
      for (int c2 = 0; c2 < 2; ++c2) {
        const int clc = cl[c2];
#pragma unroll
        for (int jj = 0; jj < 4; ++jj) {
          float a = acc[rt][c2][jj];
          float E = fexp2(a);
          float pm = (rlab[rt][jj] == clc) ? 1.f : 0.f;
          float pa = pm * a, pe = pm * E;
          SX[rt][jj] += pa; NX[rt][jj] += pm; PX[rt][jj] += pe;
          cS[c2] += pa; cN[c2] += pm; cE[c2] += pe;
        }
      }
#pragma unroll
    for (int c2 = 0; c2 < 2; ++c2) {
      cS[c2] += __shfl_xor(cS[c2], 16); cS[c2] += __shfl_xor(cS[c2], 32);
      cN[c2] += __shfl_xor(cN[c2], 16); cN[c2] += __shfl_xor(cN[c2], 32);
      cE[c2] += __shfl_xor(cE[c2], 16); cE[c2] += __shfl_xor(cE[c2], 32);
      if (lg == 0) colAcc[rw][ch4 * 32 + c2 * 16 + lr] = make_float4(cS[c2], cN[c2], cE[c2], 0.f);
    }
    ASM_LGKM0; SCHEDB;
    MEMFENCE; BARRIER; MEMFENCE;
    if (rw == 1 && lg == 0) {
#pragma unroll
      for (int c2 = 0; c2 < 2; ++c2) {
        int col = ch4 * 32 + c2 * 16 + lr;
        float4 o = colAcc[0][col];
        Cp[(i * 16 + strip) * NK + (r & 7) * 128 + col] =
            make_float4(cS[c2] + o.x, cN[c2] + o.y, (cE[c2] + o.z) * SFAC, 0.f);
      }
    }
    if (r < 14) { stage_round(r + 2); ASM_VMCNT8; MEMFENCE; BARRIER; MEMFENCE; }
    else if (r == 14) { ASM_VMCNT0; MEMFENCE; BARRIER; MEMFENCE; }
  }

  // ---- cross fold -> rredX ----
#pragma unroll
  for (int rt = 0; rt < 2; ++rt)
#pragma unroll
    for (int jj = 0; jj < 4; ++jj) {
      float a = SX[rt][jj], b4 = NX[rt][jj], c4 = PX[rt][jj];
#pragma unroll
      for (int m = 1; m <= 8; m <<= 1) {
        a += __shfl_xor(a, m); b4 += __shfl_xor(b4, m); c4 += __shfl_xor(c4, m);
      }
      if (lr == 0) rredX[ch4][rw * 32 + rt * 16 + 4 * lg + jj] = make_float4(a, b4, c4, 0.f);
    }
  __syncthreads();

  // ---- per-row pass: SNd/Rii writes + local a1 ----
  if (t < 64) {
    float4 sS = rredS[0][t], sX = rredX[0][t];
#pragma unroll
    for (int c4 = 1; c4 < 4; ++c4) {
      float4 u = rredS[c4][t], v = rredX[c4][t];
      sS.x += u.x; sS.y += u.y; sS.z += u.z; sS.w += u.w;
      sX.x += v.x; sX.y += v.y; sX.z += v.z;
    }
    float SNL = sS.w - sS.z;
    float SN = SNL * SFAC + 1e-8f;
    float LSN = __logf(SN), rSN = 1.f / SN;
    int g = i * NK + strip * 64 + t;
    SNd[g] = make_float2(LSN, rSN);
    Rii[g] = make_float4(sS.x, sS.y, sS.z * SFAC, 0.f);
    float pps = LN2 * (sS.x - CBIAS * sS.y) - sS.y * LSN - rSN * (sS.z * SFAC);
    float ppx = LN2 * (sX.x - CBIAS * sX.y) - sX.y * LSN - rSN * (sX.z * SFAC);
    float np1 = sS.y + sX.y;
    float an = 0.f, ac = 0.f;
    if (np1 > 0.f) { an = -(pps + ppx) / np1; ac = 1.f; }
#pragma unroll
    for (int m = 1; m <= 32; m <<= 1) { an += __shfl_xor(an, m); ac += __shfl_xor(ac, m); }
    if (t == 0) A1arr[i * 16 + strip] = make_float2(an, ac);
  }
  __syncthreads();

  // ---- counter dance ----
  if (t == 0) {
    __threadfence();
    int o1 = atomicAdd(&cnt[i], 1);
    int o2 = atomicAdd(&cnt[iprev], 1);
    fA = (o1 == 31); fB = (o2 == 31);
  }
  __syncthreads();

  auto pair_fold = [&](int p) {
    const int q = (p + 1) & 15;
    ACQ_AGENT;
    float an = 0.f, ac = 0.f;
    for (int r2 = t; r2 < NK; r2 += 512) {
      float4 rii = Rii[q * NK + r2];
      float2 sn = SNd[q * NK + r2];
      float cs = 0.f, cn = 0.f, ce = 0.f;
#pragma unroll
      for (int s2 = 0; s2 < 16; ++s2) {
        float4 c = Cp[(p * 16 + s2) * NK + r2];
        cs += c.x; cn += c.y; ce += c.z;
      }
      float ppc = LN2 * (cs - CBIAS * cn) - cn * sn.x - sn.y * ce;
      float ppi = LN2 * (rii.x - CBIAS * rii.y) - rii.y * sn.x - sn.y * rii.z;
      float np2 = rii.y + cn;
      if (np2 > 0.f) { an -= (ppi + ppc) / np2; ac += 1.f; }
    }
#pragma unroll
    for (int m = 1; m <= 32; m <<= 1) { an += __shfl_xor(an, m); ac += __shfl_xor(ac, m); }
    if (lane == 0) fold2[w] = make_float2(an, ac);
    __syncthreads();
    if (t == 0) {
      float a2n = 0.f, a2c = 0.f;
#pragma unroll
      for (int k2 = 0; k2 < 8; ++k2) { a2n += fold2[k2].x; a2c += fold2[k2].y; }
      float a1n = 0.f, a1c = 0.f;
#pragma unroll
      for (int s2 = 0; s2 < 16; ++s2) {
        float2 a = A1arr[q * 16 + s2];
        a1n += a.x; a1c += a.y;
      }
      Aimg[q] = make_float2(a1n + a2n, a1c + a2c);
      __threadfence();
      int f = atomicAdd(findone, 1);
      if (f == NB - 1) {
        ACQ_AGENT;
        float v = 0.f;
#pragma unroll
        for (int im = 0; im < NB; ++im) {
          float2 gg = Aimg[im];
          v += gg.x / fmaxf(gg.y, 1.f);
        }
        out[0] = v / (float)NB;
      }
    }
    __syncthreads();
  };

  if (fA) pair_fold(i);
  if (fB) pair_fold(iprev);
}

}  // namespace

extern "C" void kernel_launch(void* const* d_in, const int* in_sizes, int n_in,
                              void* d_out, int out_size, void* d_ws, size_t ws_size,
                              hipStream_t stream) {
  (void)in_sizes; (void)n_in; (void)out_size; (void)ws_size;
  const float* feats  = (const float*)d_in[0];
  const int*   labels = (const int*)d_in[1];
  float* out = (float*)d_out;
  char* ws = (char*)d_ws;

  int* sel_lab = (int*)ws;                                       // 64 KB
  unsigned short* SF = (unsigned short*)(ws + (64 << 10));       // 8 MB
  size_t off = (64 << 10) + (size_t)NB * NK * NC * 2;
  float2* SNd = (float2*)(ws + off);  off += (size_t)NB * NK * 8;       // 128 KB
  float4* Rii = (float4*)(ws + off);  off += (size_t)NB * NK * 16;      // 256 KB
  float4* Cp  = (float4*)(ws + off);  off += (size_t)NB * 16 * NK * 16; // 4 MB
  float2* A1arr = (float2*)(ws + off); off += (size_t)NB * 16 * 8;
  float2* Aimg = (float2*)(ws + off);  off += NB * 8;
  int* cnt = (int*)(ws + off);         off += 16 * 4;
  int* findone = (int*)(ws + off);

  pcl_prep<<<256, 512, 0, stream>>>(labels, feats, sel_lab, SF, cnt, findone);
  pcl_tiles<<<256, 512, 0, stream>>>(SF, sel_lab, SNd, Rii, Cp,
                                     A1arr, Aimg, cnt, findone, out);
}